// Round 5
// baseline (1299.886 us; speedup 1.0000x reference)
//
#include <hip/hip_runtime.h>
#include <math.h>

#define NROWS_TOTAL 524288
#define BR 64
#define NTH 512
#define PI_F 3.14159265358979323846f
#define TWO_PI_F 6.28318530717958647692f

typedef float f32x4 __attribute__((ext_vector_type(4)));
typedef _Float16 half8 __attribute__((ext_vector_type(8)));
typedef _Float16 half4v __attribute__((ext_vector_type(4)));

// LDS layout (bytes). Activations: f16 hi plane rows 0..63, lo plane rows 64..127.
#define OFF_A 0
#define OFF_B 67584          // = 128 * 528
#define LDS_BYTES 135168     // two regions of 67584
#define PITCH_ACT 528        // 264 f16 (33 x 16B units, odd -> 2-way-free b128 reads)
#define PITCH_OUT 1540       // 385 f32 words (odd -> conflict-free scalar reads); logits f32
#define OFF_LAD 100352       // past logits end (98556), within LDS

// ws layout (f16 elements): hi arrays then lo arrays at +204800
#define W1_OFF 0             // 256 x 160 (K padded 140->160 with zeros)
#define W2_OFF 40960         // 256 x 256
#define W3_OFF 106496        // 384 x 256
#define WHI_TOT 204800

struct h2 { _Float16 hi, lo; };
__device__ __forceinline__ h2 split16(float v){
  h2 r;
  r.hi = (_Float16)v;
  r.lo = (_Float16)(v - (float)r.hi);
  return r;
}

// One fused GEMM: dst[n][o] = act(src[n][:] . W[o][:] + bias[o]).
// A (hi/lo f16) from LDS; W (hi/lo f16) straight from global (L2-resident).
// No barriers inside the k-loop; 3 MFMA passes give ~f32-exact products.
template<int NK, int NCT, bool RELU, bool OUTF32>
__device__ __forceinline__ void gemm_phase(unsigned char* LDS,
    const _Float16* __restrict__ WH, const _Float16* __restrict__ WL,
    const float* __restrict__ bias,
    int srcOff, int dstOff, int wave, int lrow, int lhi)
{
  constexpr int NS = NK / 32;
  f32x4 acc[4][NCT];
  #pragma unroll
  for (int rg = 0; rg < 4; rg++)
    #pragma unroll
    for (int ct = 0; ct < NCT; ct++)
      acc[rg][ct] = (f32x4){0.f, 0.f, 0.f, 0.f};

  const int ko = lhi * 8;
  #pragma unroll
  for (int ksl = 0; ksl < NS; ksl++){
    half8 ah[4], al[4];
    #pragma unroll
    for (int rg = 0; rg < 4; rg++){
      const unsigned char* p = LDS + srcOff + (rg * 16 + lrow) * PITCH_ACT
                               + (ksl * 32 + ko) * 2;
      ah[rg] = *(const half8*)p;
      al[rg] = *(const half8*)(p + 64 * PITCH_ACT);
    }
    #pragma unroll
    for (int ct = 0; ct < NCT; ct++){
      const int o = (wave * NCT + ct) * 16 + lrow;
      const size_t woff = (size_t)o * NK + ksl * 32 + ko;
      half8 wh = *(const half8*)(WH + woff);
      half8 wl = *(const half8*)(WL + woff);
      #pragma unroll
      for (int rg = 0; rg < 4; rg++){
        acc[rg][ct] = __builtin_amdgcn_mfma_f32_16x16x32_f16(ah[rg], wh, acc[rg][ct], 0, 0, 0);
        acc[rg][ct] = __builtin_amdgcn_mfma_f32_16x16x32_f16(al[rg], wh, acc[rg][ct], 0, 0, 0);
        acc[rg][ct] = __builtin_amdgcn_mfma_f32_16x16x32_f16(ah[rg], wl, acc[rg][ct], 0, 0, 0);
      }
    }
  }
  __syncthreads();   // all src reads done before dst writes (dst may overlap src)
  #pragma unroll
  for (int ct = 0; ct < NCT; ct++){
    const int col = (wave * NCT + ct) * 16 + lrow;
    const float bv = bias[col];
    #pragma unroll
    for (int rg = 0; rg < 4; rg++){
      #pragma unroll
      for (int j = 0; j < 4; j++){
        float v = acc[rg][ct][j] + bv;
        if (RELU) v = (v >= 0.f) ? v : 0.01f * v;
        const int row = rg * 16 + lhi * 4 + j;
        if (OUTF32){
          *(float*)(LDS + (size_t)row * PITCH_OUT + col * 4) = v;
        } else {
          h2 s = split16(v);
          *(_Float16*)(LDS + dstOff + row * PITCH_ACT + col * 2) = s.hi;
          *(_Float16*)(LDS + dstOff + (row + 64) * PITCH_ACT + col * 2) = s.lo;
        }
      }
    }
  }
  __syncthreads();   // dst visible to all
}

__global__ void wconv_kernel(const float* __restrict__ W1, const float* __restrict__ W2,
                             const float* __restrict__ W3, _Float16* __restrict__ wb)
{
  int i = blockIdx.x * 256 + threadIdx.x;   // 800*256 = 204800 exactly
  float v;
  if (i < 40960){
    int o = i / 160, k = i - o * 160;
    v = (k < 140) ? W1[o * 140 + k] : 0.f;
  } else if (i < 106496){
    v = W2[i - 40960];
  } else {
    v = W3[i - 106496];
  }
  h2 s = split16(v);
  wb[i] = s.hi;
  wb[i + WHI_TOT] = s.lo;
}

__global__ __launch_bounds__(NTH, 2) void spline_fused(
    const float* __restrict__ x, const float* __restrict__ c,
    const float* __restrict__ b1, const float* __restrict__ b2,
    const float* __restrict__ b3, const _Float16* __restrict__ wb,
    const int* __restrict__ invp, float* __restrict__ out)
{
  __shared__ __align__(16) unsigned char LDS[LDS_BYTES];
  const int tid  = threadIdx.x;
  const int wave = tid >> 6;
  const int lane = tid & 63;
  const int lrow = lane & 15;
  const int lhi  = lane >> 4;
  const int row0 = blockIdx.x * BR;

  // ---- P0: build inp (region B): [xc(4) sin(4) cos(4) c(128) zeros(20)] f16 hi/lo
  {
    const float4* c4 = (const float4*)(c + (size_t)row0 * 128);
    #pragma unroll
    for (int i = 0; i < 4; i++){
      int q = tid + i * NTH;                 // 0..2047 float4s of the c block
      float4 v = c4[q];
      int r = q >> 5, cg = (q & 31) * 4 + 12;
      h2 s0 = split16(v.x), s1 = split16(v.y), s2 = split16(v.z), s3 = split16(v.w);
      half4v hv = {s0.hi, s1.hi, s2.hi, s3.hi};
      half4v lv = {s0.lo, s1.lo, s2.lo, s3.lo};
      *(half4v*)(LDS + OFF_B + r * PITCH_ACT + cg * 2) = hv;
      *(half4v*)(LDS + OFF_B + (r + 64) * PITCH_ACT + cg * 2) = lv;
    }
    if (tid < BR){
      int n = row0 + tid;
      float4 xa = *(const float4*)(x + (size_t)n * 8);
      float4 xb = *(const float4*)(x + (size_t)n * 8 + 4);
      float xc0 = xa.y, xc1 = xa.w, xc2 = xb.y, xc3 = xb.w;  // cond dims 1,3,5,7
      float f[12] = {xc0, xc1, xc2, xc3,
                     sinf(xc0), sinf(xc1), sinf(xc2), sinf(xc3),
                     cosf(xc0), cosf(xc1), cosf(xc2), cosf(xc3)};
      unsigned char* rp = LDS + OFF_B + tid * PITCH_ACT;
      #pragma unroll
      for (int g = 0; g < 3; g++){
        h2 s0 = split16(f[4*g+0]), s1 = split16(f[4*g+1]);
        h2 s2 = split16(f[4*g+2]), s3 = split16(f[4*g+3]);
        half4v hv = {s0.hi, s1.hi, s2.hi, s3.hi};
        half4v lv = {s0.lo, s1.lo, s2.lo, s3.lo};
        *(half4v*)(rp + g * 8) = hv;
        *(half4v*)(rp + 64 * PITCH_ACT + g * 8) = lv;
      }
      #pragma unroll
      for (int z = 0; z < 5; z++){           // zero-pad cols 140..159, both planes
        *(unsigned long long*)(rp + 280 + z * 8) = 0ull;
        *(unsigned long long*)(rp + 64 * PITCH_ACT + 280 + z * 8) = 0ull;
      }
    }
  }
  __syncthreads();

  // ---- three fused GEMMs (split-f16, ~f32-exact)
  const _Float16* WLO = wb + WHI_TOT;
  gemm_phase<160, 2, true , false>(LDS, wb + W1_OFF, WLO + W1_OFF, b1, OFF_B, OFF_A, wave, lrow, lhi);
  gemm_phase<256, 2, true , false>(LDS, wb + W2_OFF, WLO + W2_OFF, b2, OFF_A, OFF_B, wave, lrow, lhi);
  gemm_phase<256, 3, false, true >(LDS, wb + W3_OFF, WLO + W3_OFF, b3, OFF_B, 0,     wave, lrow, lhi);

  // ---- spline: one thread per (row, dim); 256 threads = 64 rows x 4 dims
  if (tid < 256){
    const int r = tid & 63;
    const int d = tid >> 6;
    const int n = row0 + r;
    const int inv = invp[0];

    const float* ob = (const float*)(LDS + (size_t)r * PITCH_OUT) + d * 96;

    float wn[32], hn[32];
    float mw = ob[0], mh = ob[1];
    #pragma unroll
    for (int b = 1; b < 32; b++){
      mw = fmaxf(mw, ob[3*b]);
      mh = fmaxf(mh, ob[3*b + 1]);
    }
    float sw = 0.f, sh = 0.f;
    #pragma unroll
    for (int b = 0; b < 32; b++){
      float ew = expf(ob[3*b] - mw);     wn[b] = ew; sw += ew;
      float eh = expf(ob[3*b + 1] - mh); hn[b] = eh; sh += eh;
    }
    const float C1 = 1.0f - 32.0f * 1e-3f;
    float iw = C1 / sw, ih = C1 / sh;
    #pragma unroll
    for (int b = 0; b < 32; b++){
      wn[b] = 1e-3f + wn[b] * iw;
      hn[b] = 1e-3f + hn[b] * ih;
    }

    float2 xv = *(const float2*)(x + (size_t)n * 8 + 2 * d);
    float xm = xv.x, xcv = xv.y;

    // bin search on (inv ? cumh : cumw); capture lo edge + width (no dyn indexing)
    bool fnd = false; int idx = 31;
    float cw = -PI_F, loA = 0.f, szA = 0.f;
    #pragma unroll
    for (int b = 0; b < 31; b++){
      float wbv = TWO_PI_F * (inv ? hn[b] : wn[b]);
      float reb = cw + wbv;
      if (!fnd && xm < reb){ fnd = true; idx = b; loA = cw; szA = wbv; }
      cw = reb;
    }
    if (!fnd){ loA = cw; szA = PI_F - cw; }

    // scan the other cumulative at idx
    float ch = -PI_F, loB = 0.f, szB = 0.f;
    #pragma unroll
    for (int b = 0; b < 31; b++){
      float hbv = TWO_PI_F * (inv ? wn[b] : hn[b]);
      if (b == idx){ loB = ch; szB = hbv; }
      ch += hbv;
    }
    if (idx == 31){ loB = ch; szB = PI_F - ch; }

    float le, wbw, lh, hb;
    if (inv){ lh = loA; hb = szA; le = loB; wbw = szB; }
    else    { le = loA; wbw = szA; lh = loB; hb = szB; }

    // derivatives: only d[idx], d[idx+1] needed; circular d[32]=d[0]
    int i2 = (idx + 1) & 31;
    float ud0 = ob[idx * 3 + 2];
    float ud1 = ob[i2  * 3 + 2];
    auto softplus = [](float v) -> float {
      return fmaxf(v, 0.f) + log1pf(expf(-fabsf(v)));
    };
    float d0 = 1e-3f + softplus(ud0);
    float d1 = 1e-3f + softplus(ud1);

    float delta = hb / wbw;
    float outv, lad;
    if (inv){
      float dy = xm - lh;
      float s  = d0 + d1 - 2.f * delta;
      float aq = dy * s + hb * (delta - d0);
      float bq = hb * d0 - dy * s;
      float cq = -delta * dy;
      float disc = bq * bq - 4.f * aq * cq;
      float root = (2.f * cq) / (-bq - sqrtf(disc));
      outv = root * wbw + le;
      float t1m = root * (1.f - root);
      float denom = delta + s * t1m;
      float dnum = delta * delta * (d1 * root * root + 2.f * delta * t1m + d0 * (1.f - root) * (1.f - root));
      lad = -(logf(dnum) - 2.f * logf(denom));
    } else {
      float theta = (xm - le) / wbw;
      float t1m = theta * (1.f - theta);
      float s   = d0 + d1 - 2.f * delta;
      float denom = delta + s * t1m;
      float num = hb * (delta * theta * theta + d0 * t1m);
      outv = lh + num / denom;
      float dnum = delta * delta * (d1 * theta * theta + 2.f * delta * t1m + d0 * (1.f - theta) * (1.f - theta));
      lad = logf(dnum) - 2.f * logf(denom);
    }

    out[(size_t)n * 8 + 2 * d]     = outv;   // mapping dims -> even cols
    out[(size_t)n * 8 + 2 * d + 1] = xcv;    // cond dims pass through -> odd cols
    *(float*)(LDS + OFF_LAD + (r * 4 + d) * 4) = lad;
  }
  __syncthreads();
  if (tid < BR){
    const float* lp = (const float*)(LDS + OFF_LAD);
    float sld = lp[tid * 4] + lp[tid * 4 + 1] + lp[tid * 4 + 2] + lp[tid * 4 + 3];
    out[(size_t)NROWS_TOTAL * 8 + row0 + tid] = sld;
  }
}

extern "C" void kernel_launch(void* const* d_in, const int* in_sizes, int n_in,
                              void* d_out, int out_size, void* d_ws, size_t ws_size,
                              hipStream_t stream)
{
  (void)in_sizes; (void)n_in; (void)out_size; (void)ws_size;
  const float* x  = (const float*)d_in[0];
  const float* c  = (const float*)d_in[1];
  const float* W1 = (const float*)d_in[2];
  const float* b1 = (const float*)d_in[3];
  const float* W2 = (const float*)d_in[4];
  const float* b2 = (const float*)d_in[5];
  const float* W3 = (const float*)d_in[6];
  const float* b3 = (const float*)d_in[7];
  const int*  inv = (const int*)d_in[8];
  _Float16* wb = (_Float16*)d_ws;
  float* out = (float*)d_out;

  hipLaunchKernelGGL(wconv_kernel, dim3(800), dim3(256), 0, stream, W1, W2, W3, wb);
  hipLaunchKernelGGL(spline_fused, dim3(NROWS_TOTAL / BR), dim3(NTH), 0, stream,
                     x, c, b1, b2, b3, wb, inv, out);
}

// Round 9
// 1098.244 us; speedup vs baseline: 1.1836x; 1.1836x over previous
//
#include <hip/hip_runtime.h>
#include <math.h>

#define NROWS_TOTAL 524288
#define BR 64
#define NTH 512
#define PI_F 3.14159265358979323846f
#define TWO_PI_F 6.28318530717958647692f

typedef float f32x4 __attribute__((ext_vector_type(4)));
typedef _Float16 half8 __attribute__((ext_vector_type(8)));
typedef _Float16 half4v __attribute__((ext_vector_type(4)));

// Single in-place LDS region: activations (f16 hi rows 0..63, lo rows 64..127,
// pitch 528B) are overwritten phase-by-phase (all reads complete before the
// pre-epilogue barrier). Phase-3 f32 logits (pitch 1540B, 32 rows = 49KB)
// overlay the same region in two row-halves.
#define PITCH_ACT 528        // 264 f16 (33 x 16B units, odd)
#define PITCH_OUT 1540       // 385 f32 words (odd -> 2-way max on reads)
#define OFF_LAD 67584        // lad scratch (64*4 f32) after act region
#define LDS_BYTES 68608      // -> 2 blocks/CU

// ws layout (f16 elements): hi arrays then lo arrays at +204800
#define W1_OFF 0             // 256 x 160 (K padded 140->160 with zeros)
#define W2_OFF 40960         // 256 x 256
#define W3_OFF 106496        // 384 x 256
#define WHI_TOT 204800

struct h2 { _Float16 hi, lo; };
__device__ __forceinline__ h2 split16(float v){
  h2 r;
  r.hi = (_Float16)v;
  r.lo = (_Float16)(v - (float)r.hi);
  return r;
}

// K-loop with explicit double-buffered weight prefetch (fully unrolled ->
// static buffer indices). A-frags loaded per-rg (8 regs live) to fit VGPR<=128.
template<int NK, int NCT>
__device__ __forceinline__ void gemm_core(const unsigned char* LDS,
    f32x4 (&acc)[4][NCT],
    const _Float16* __restrict__ WH, const _Float16* __restrict__ WL,
    int wave, int lrow, int lhi)
{
  constexpr int NS = NK / 32;
  #pragma unroll
  for (int rg = 0; rg < 4; rg++)
    #pragma unroll
    for (int ct = 0; ct < NCT; ct++)
      acc[rg][ct] = (f32x4){0.f, 0.f, 0.f, 0.f};

  const int ko = lhi * 8;
  half8 whb[2][NCT], wlb[2][NCT];
  #pragma unroll
  for (int ct = 0; ct < NCT; ct++){
    const int o = (wave * NCT + ct) * 16 + lrow;
    whb[0][ct] = *(const half8*)(WH + (size_t)o * NK + ko);
    wlb[0][ct] = *(const half8*)(WL + (size_t)o * NK + ko);
  }
  #pragma unroll
  for (int ksl = 0; ksl < NS; ksl++){
    const int cur = ksl & 1, nxt = cur ^ 1;
    if (ksl + 1 < NS){
      #pragma unroll
      for (int ct = 0; ct < NCT; ct++){
        const int o = (wave * NCT + ct) * 16 + lrow;
        const size_t woff = (size_t)o * NK + (ksl + 1) * 32 + ko;
        whb[nxt][ct] = *(const half8*)(WH + woff);
        wlb[nxt][ct] = *(const half8*)(WL + woff);
      }
    }
    #pragma unroll
    for (int rg = 0; rg < 4; rg++){
      const unsigned char* p = LDS + (rg * 16 + lrow) * PITCH_ACT + (ksl * 32 + ko) * 2;
      half8 ah = *(const half8*)p;
      half8 al = *(const half8*)(p + 64 * PITCH_ACT);
      #pragma unroll
      for (int ct = 0; ct < NCT; ct++){
        acc[rg][ct] = __builtin_amdgcn_mfma_f32_16x16x32_f16(ah, whb[cur][ct], acc[rg][ct], 0, 0, 0);
        acc[rg][ct] = __builtin_amdgcn_mfma_f32_16x16x32_f16(al, whb[cur][ct], acc[rg][ct], 0, 0, 0);
        acc[rg][ct] = __builtin_amdgcn_mfma_f32_16x16x32_f16(ah, wlb[cur][ct], acc[rg][ct], 0, 0, 0);
      }
    }
  }
}

// f16 hi/lo epilogue (phases 1,2), in-place into the act region.
template<int NCT>
__device__ __forceinline__ void epi_f16(unsigned char* LDS, f32x4 (&acc)[4][NCT],
    const float* __restrict__ bias, int wave, int lrow, int lhi)
{
  #pragma unroll
  for (int ct = 0; ct < NCT; ct++){
    const int col = (wave * NCT + ct) * 16 + lrow;
    const float bv = bias[col];
    #pragma unroll
    for (int rg = 0; rg < 4; rg++){
      #pragma unroll
      for (int j = 0; j < 4; j++){
        float v = acc[rg][ct][j] + bv;
        v = (v >= 0.f) ? v : 0.01f * v;
        const int row = rg * 16 + lhi * 4 + j;
        h2 s = split16(v);
        *(_Float16*)(LDS + row * PITCH_ACT + col * 2) = s.hi;
        *(_Float16*)(LDS + (row + 64) * PITCH_ACT + col * 2) = s.lo;
      }
    }
  }
}

// f32 logits epilogue for one row-half (rgBase = 0 -> rows 0..31, 2 -> 32..63).
template<int NCT>
__device__ __forceinline__ void epi_logits(unsigned char* LDS, f32x4 (&acc)[4][NCT],
    const float* __restrict__ bias, int rgBase, int wave, int lrow, int lhi)
{
  #pragma unroll
  for (int ct = 0; ct < NCT; ct++){
    const int col = (wave * NCT + ct) * 16 + lrow;
    const float bv = bias[col];
    #pragma unroll
    for (int rg = 0; rg < 2; rg++){
      #pragma unroll
      for (int j = 0; j < 4; j++){
        const int rowl = rg * 16 + lhi * 4 + j;   // 0..31 within the half
        *(float*)(LDS + (size_t)rowl * PITCH_OUT + col * 4)
            = acc[rgBase + rg][ct][j] + bv;
      }
    }
  }
}

__device__ __forceinline__ void spline_half(unsigned char* LDS, int half, int tid,
    int row0, const float* __restrict__ x, int inv, float* __restrict__ out)
{
  if (tid >= 128) return;
  const int lr = tid & 31;          // row within the half
  const int d  = tid >> 5;          // mapping dim 0..3
  const int r  = half * 32 + lr;    // row within block
  const int n  = row0 + r;

  const float* ob = (const float*)(LDS + (size_t)lr * PITCH_OUT) + d * 96;

  float wn[32], hn[32];
  float mw = ob[0], mh = ob[1];
  #pragma unroll
  for (int b = 1; b < 32; b++){
    mw = fmaxf(mw, ob[3*b]);
    mh = fmaxf(mh, ob[3*b + 1]);
  }
  float sw = 0.f, sh = 0.f;
  #pragma unroll
  for (int b = 0; b < 32; b++){
    float ew = expf(ob[3*b] - mw);     wn[b] = ew; sw += ew;
    float eh = expf(ob[3*b + 1] - mh); hn[b] = eh; sh += eh;
  }
  const float C1 = 1.0f - 32.0f * 1e-3f;
  float iw = C1 / sw, ih = C1 / sh;
  #pragma unroll
  for (int b = 0; b < 32; b++){
    wn[b] = 1e-3f + wn[b] * iw;
    hn[b] = 1e-3f + hn[b] * ih;
  }

  float2 xv = *(const float2*)(x + (size_t)n * 8 + 2 * d);
  float xm = xv.x, xcv = xv.y;

  // bin search on (inv ? cumh : cumw); capture lo edge + width (no dyn indexing)
  bool fnd = false; int idx = 31;
  float cw = -PI_F, loA = 0.f, szA = 0.f;
  #pragma unroll
  for (int b = 0; b < 31; b++){
    float wbv = TWO_PI_F * (inv ? hn[b] : wn[b]);
    float reb = cw + wbv;
    if (!fnd && xm < reb){ fnd = true; idx = b; loA = cw; szA = wbv; }
    cw = reb;
  }
  if (!fnd){ loA = cw; szA = PI_F - cw; }

  float ch = -PI_F, loB = 0.f, szB = 0.f;
  #pragma unroll
  for (int b = 0; b < 31; b++){
    float hbv = TWO_PI_F * (inv ? wn[b] : hn[b]);
    if (b == idx){ loB = ch; szB = hbv; }
    ch += hbv;
  }
  if (idx == 31){ loB = ch; szB = PI_F - ch; }

  float le, wbw, lh, hb;
  if (inv){ lh = loA; hb = szA; le = loB; wbw = szB; }
  else    { le = loA; wbw = szA; lh = loB; hb = szB; }

  int i2 = (idx + 1) & 31;
  float ud0 = ob[idx * 3 + 2];
  float ud1 = ob[i2  * 3 + 2];
  auto softplus = [](float v) -> float {
    return fmaxf(v, 0.f) + log1pf(expf(-fabsf(v)));
  };
  float d0 = 1e-3f + softplus(ud0);
  float d1 = 1e-3f + softplus(ud1);

  float delta = hb / wbw;
  float outv, lad;
  if (inv){
    float dy = xm - lh;
    float s  = d0 + d1 - 2.f * delta;
    float aq = dy * s + hb * (delta - d0);
    float bq = hb * d0 - dy * s;
    float cq = -delta * dy;
    float disc = bq * bq - 4.f * aq * cq;
    float root = (2.f * cq) / (-bq - sqrtf(disc));
    outv = root * wbw + le;
    float t1m = root * (1.f - root);
    float denom = delta + s * t1m;
    float dnum = delta * delta * (d1 * root * root + 2.f * delta * t1m + d0 * (1.f - root) * (1.f - root));
    lad = -(logf(dnum) - 2.f * logf(denom));
  } else {
    float theta = (xm - le) / wbw;
    float t1m = theta * (1.f - theta);
    float s   = d0 + d1 - 2.f * delta;
    float denom = delta + s * t1m;
    float num = hb * (delta * theta * theta + d0 * t1m);
    outv = lh + num / denom;
    float dnum = delta * delta * (d1 * theta * theta + 2.f * delta * t1m + d0 * (1.f - theta) * (1.f - theta));
    lad = logf(dnum) - 2.f * logf(denom);
  }

  out[(size_t)n * 8 + 2 * d]     = outv;   // mapping dims -> even cols
  out[(size_t)n * 8 + 2 * d + 1] = xcv;    // cond dims pass through -> odd cols
  *(float*)(LDS + OFF_LAD + (r * 4 + d) * 4) = lad;
}

__global__ void wconv_kernel(const float* __restrict__ W1, const float* __restrict__ W2,
                             const float* __restrict__ W3, _Float16* __restrict__ wb)
{
  int i = blockIdx.x * 256 + threadIdx.x;   // 800*256 = 204800 exactly
  float v;
  if (i < 40960){
    int o = i / 160, k = i - o * 160;
    v = (k < 140) ? W1[o * 140 + k] : 0.f;
  } else if (i < 106496){
    v = W2[i - 40960];
  } else {
    v = W3[i - 106496];
  }
  h2 s = split16(v);
  wb[i] = s.hi;
  wb[i + WHI_TOT] = s.lo;
}

__global__ __launch_bounds__(NTH, 4) void spline_fused(
    const float* __restrict__ x, const float* __restrict__ c,
    const float* __restrict__ b1, const float* __restrict__ b2,
    const float* __restrict__ b3, const _Float16* __restrict__ wb,
    const int* __restrict__ invp, float* __restrict__ out)
{
  __shared__ __align__(16) unsigned char LDS[LDS_BYTES];
  const int tid  = threadIdx.x;
  const int wave = tid >> 6;
  const int lane = tid & 63;
  const int lrow = lane & 15;
  const int lhi  = lane >> 4;
  const int row0 = blockIdx.x * BR;

  // ---- P0: build inp: [xc(4) sin(4) cos(4) c(128) zeros(20)] f16 hi/lo
  {
    const float4* c4 = (const float4*)(c + (size_t)row0 * 128);
    #pragma unroll
    for (int i = 0; i < 4; i++){
      int q = tid + i * NTH;                 // 0..2047 float4s of the c block
      float4 v = c4[q];
      int r = q >> 5, cg = (q & 31) * 4 + 12;
      h2 s0 = split16(v.x), s1 = split16(v.y), s2 = split16(v.z), s3 = split16(v.w);
      half4v hv = {s0.hi, s1.hi, s2.hi, s3.hi};
      half4v lv = {s0.lo, s1.lo, s2.lo, s3.lo};
      *(half4v*)(LDS + r * PITCH_ACT + cg * 2) = hv;
      *(half4v*)(LDS + (r + 64) * PITCH_ACT + cg * 2) = lv;
    }
    if (tid < BR){
      int n = row0 + tid;
      float4 xa = *(const float4*)(x + (size_t)n * 8);
      float4 xb = *(const float4*)(x + (size_t)n * 8 + 4);
      float xc0 = xa.y, xc1 = xa.w, xc2 = xb.y, xc3 = xb.w;  // cond dims 1,3,5,7
      float f[12] = {xc0, xc1, xc2, xc3,
                     sinf(xc0), sinf(xc1), sinf(xc2), sinf(xc3),
                     cosf(xc0), cosf(xc1), cosf(xc2), cosf(xc3)};
      unsigned char* rp = LDS + tid * PITCH_ACT;
      #pragma unroll
      for (int g = 0; g < 3; g++){
        h2 s0 = split16(f[4*g+0]), s1 = split16(f[4*g+1]);
        h2 s2 = split16(f[4*g+2]), s3 = split16(f[4*g+3]);
        half4v hv = {s0.hi, s1.hi, s2.hi, s3.hi};
        half4v lv = {s0.lo, s1.lo, s2.lo, s3.lo};
        *(half4v*)(rp + g * 8) = hv;
        *(half4v*)(rp + 64 * PITCH_ACT + g * 8) = lv;
      }
      #pragma unroll
      for (int z = 0; z < 5; z++){           // zero-pad cols 140..159, both planes
        *(unsigned long long*)(rp + 280 + z * 8) = 0ull;
        *(unsigned long long*)(rp + 64 * PITCH_ACT + 280 + z * 8) = 0ull;
      }
    }
  }
  __syncthreads();

  const _Float16* WLO = wb + WHI_TOT;
  const int inv = invp[0];

  { // phase 1: 160 -> 256, leaky relu, in-place
    f32x4 acc[4][2];
    gemm_core<160, 2>(LDS, acc, wb + W1_OFF, WLO + W1_OFF, wave, lrow, lhi);
    __syncthreads();
    epi_f16<2>(LDS, acc, b1, wave, lrow, lhi);
  }
  __syncthreads();
  { // phase 2: 256 -> 256, leaky relu, in-place
    f32x4 acc[4][2];
    gemm_core<256, 2>(LDS, acc, wb + W2_OFF, WLO + W2_OFF, wave, lrow, lhi);
    __syncthreads();
    epi_f16<2>(LDS, acc, b2, wave, lrow, lhi);
  }
  __syncthreads();
  { // phase 3: 256 -> 384 logits; two row-halves overlaying the act region
    f32x4 acc[4][3];
    gemm_core<256, 3>(LDS, acc, wb + W3_OFF, WLO + W3_OFF, wave, lrow, lhi);
    __syncthreads();                                   // all h2 reads done
    epi_logits<3>(LDS, acc, b3, 0, wave, lrow, lhi);   // rows 0..31
    __syncthreads();
    spline_half(LDS, 0, tid, row0, x, inv, out);
    __syncthreads();                                   // spline A reads done
    epi_logits<3>(LDS, acc, b3, 2, wave, lrow, lhi);   // rows 32..63
    __syncthreads();
    spline_half(LDS, 1, tid, row0, x, inv, out);
  }
  __syncthreads();
  if (tid < BR){
    float4 v = *(const float4*)(LDS + OFF_LAD + tid * 16);
    out[(size_t)NROWS_TOTAL * 8 + row0 + tid] = v.x + v.y + v.z + v.w;
  }
}

extern "C" void kernel_launch(void* const* d_in, const int* in_sizes, int n_in,
                              void* d_out, int out_size, void* d_ws, size_t ws_size,
                              hipStream_t stream)
{
  (void)in_sizes; (void)n_in; (void)out_size; (void)ws_size;
  const float* x  = (const float*)d_in[0];
  const float* c  = (const float*)d_in[1];
  const float* W1 = (const float*)d_in[2];
  const float* b1 = (const float*)d_in[3];
  const float* W2 = (const float*)d_in[4];
  const float* b2 = (const float*)d_in[5];
  const float* W3 = (const float*)d_in[6];
  const float* b3 = (const float*)d_in[7];
  const int*  inv = (const int*)d_in[8];
  _Float16* wb = (_Float16*)d_ws;
  float* out = (float*)d_out;

  hipLaunchKernelGGL(wconv_kernel, dim3(800), dim3(256), 0, stream, W1, W2, W3, wb);
  hipLaunchKernelGGL(spline_fused, dim3(NROWS_TOTAL / BR), dim3(NTH), 0, stream,
                     x, c, b1, b2, b3, wb, inv, out);
}